// Round 4
// baseline (168.658 us; speedup 1.0000x reference)
//
#include <hip/hip_runtime.h>
#include <hip/hip_bf16.h>

#define N_ROWS 8192
#define BATCH 4096
#define DIM 256

#define NB 64           // 128-row blocks along each side
#define BR 128          // rows (and cols) per pair-block side
#define CT 16           // cols per tile
#define NT 8            // tiles per block (BR/CT)
#define NBLK (NB * (NB + 1) / 2)   // 2080 pair blocks
#define KEXP 2.8853900817779268f   // 2*log2(e): exp(2*dot) = exp2(dot*KEXP)

typedef __attribute__((ext_vector_type(8))) short bfrag8;
typedef __attribute__((ext_vector_type(4))) float facc4;

// ---------------- Kernel A: normalize + cast to bf16 -------------------
__global__ __launch_bounds__(256) void normalize_kernel(
    const float* __restrict__ zA, const float* __restrict__ zB,
    __hip_bfloat16* __restrict__ zn) {
    int tid = threadIdx.x;
    int wave = tid >> 6, lane = tid & 63;
    int row = blockIdx.x * 4 + wave;
    const float* src = (row < BATCH) ? (zA + (size_t)row * DIM)
                                     : (zB + (size_t)(row - BATCH) * DIM);
    float4 v = ((const float4*)src)[lane];
    float ss = v.x * v.x + v.y * v.y + v.z * v.z + v.w * v.w;
    #pragma unroll
    for (int m = 32; m; m >>= 1) ss += __shfl_xor(ss, m);
    float inv = 1.0f / fmaxf(sqrtf(ss), 1e-8f);
    union { ushort4 u; __hip_bfloat16 h[4]; } o;
    o.h[0] = __float2bfloat16(v.x * inv);
    o.h[1] = __float2bfloat16(v.y * inv);
    o.h[2] = __float2bfloat16(v.z * inv);
    o.h[3] = __float2bfloat16(v.w * inv);
    ((ushort4*)zn)[(size_t)row * (DIM / 4) + lane] = o.u;
}

// ---------------- Kernel B: symmetric pair-block sim + exp-sum ---------
// Grid: 2080 blocks, one per unordered pair (bi <= bj):
//   row-sums of exp -> ep[bj][rows of bi]
//   col-sums of exp -> ep[bi][cols of bj]   (bi != bj only)
// One write per ep cell, no atomics, no memset.
//
// NO LDS staging, NO in-loop barriers: zn is 4 MB (fits one XCD L2; swizzle
// keeps the panel hot). B fragments load straight from L2 into registers,
// double-buffered (bfA/bfB, static indexing) so tile t+1 loads hide under
// tile t's 16 MFMAs + exp. Rounds 0-3 showed the LDS/barrier scaffold was
// the invariant cost (work halved twice, time unchanged, all pipes <25%,
// barrier count constant) -- this deletes it.
__global__ __launch_bounds__(256, 3) void ntxent_main(
    const __hip_bfloat16* __restrict__ zn_,
    float* __restrict__ ep, float* __restrict__ pp) {
    const char* zn = (const char*)zn_;
    __shared__ float colbuf[4][BR];
    int tid = threadIdx.x, lane = tid & 63, wave = tid >> 6;
    int quad = lane >> 4, l15 = lane & 15;

    // XCD-aware swizzle (bijective: 2080 % 8 == 0)
    int bid = blockIdx.x;
    int k = (bid & 7) * (NBLK / 8) + (bid >> 3);

    // decode linear pair id -> (bi, bj), bi <= bj
    int bi = (int)(0.5f * (129.0f - sqrtf(16641.0f - 8.0f * (float)k)));
    if (bi < 0) bi = 0;
    if (bi > NB - 1) bi = NB - 1;
    while (bi * (129 - bi) / 2 > k) --bi;
    while ((bi + 1) * (128 - bi) / 2 <= k) ++bi;
    int bj = bi + (k - bi * (129 - bi) / 2);
    bool diagblk = (bi == bj);

    int row0 = bi * BR + wave * 32;   // this wave's 32 rows

    // B column base for this lane: col = bj*BR + t*CT + l15, bytes quad*16+ks*64
    const char* gB = zn + (size_t)(bj * BR + l15) * 512 + quad * 16;

    bfrag8 bfA[8], bfB[8];
    #pragma unroll
    for (int ks = 0; ks < 8; ks++)              // prefetch tile 0
        bfA[ks] = *(const bfrag8*)(gB + ks * 64);

    // A fragments: 2 tiles of 16 rows, full K=256 (overlaps tile-0 loads)
    bfrag8 a[2][8];
    #pragma unroll
    for (int s = 0; s < 2; s++) {
        const char* ap = zn + (size_t)(row0 + s * 16 + l15) * 512 + quad * 16;
        #pragma unroll
        for (int ks = 0; ks < 8; ks++)
            a[s][ks] = *(const bfrag8*)(ap + ks * 64);
    }

    float es[2][4];
    #pragma unroll
    for (int s = 0; s < 2; s++)
        #pragma unroll
        for (int r = 0; r < 4; r++) es[s][r] = 0.f;

    auto compute_tile = [&](int t, bfrag8 (&bf)[8]) {
        facc4 acc[2];
        acc[0] = (facc4){0.f, 0.f, 0.f, 0.f};
        acc[1] = (facc4){0.f, 0.f, 0.f, 0.f};
        #pragma unroll
        for (int ks = 0; ks < 8; ks++) {
            acc[0] = __builtin_amdgcn_mfma_f32_16x16x32_bf16(a[0][ks], bf[ks], acc[0], 0, 0, 0);
            acc[1] = __builtin_amdgcn_mfma_f32_16x16x32_bf16(a[1][ks], bf[ks], acc[1], 0, 0, 0);
        }
        int ctile = bj * BR + t * CT;
        int gcol = ctile + l15;
        float ce = 0.0f;
        bool isdiag = (ctile >> 5) == (row0 >> 5);             // only in diag blocks
        bool ispos  = (ctile >> 5) == ((row0 ^ BATCH) >> 5);   // only in (bi, bi+32)

        if (isdiag) {
            #pragma unroll
            for (int s = 0; s < 2; s++)
                #pragma unroll
                for (int r = 0; r < 4; r++) {
                    int grow = row0 + s * 16 + quad * 4 + r;
                    float e = __builtin_amdgcn_exp2f(acc[s][r] * KEXP);
                    if (gcol == grow) e = 0.0f;   // mask true diagonal
                    es[s][r] += e; ce += e;
                }
        } else {
            #pragma unroll
            for (int s = 0; s < 2; s++)
                #pragma unroll
                for (int r = 0; r < 4; r++) {
                    float e = __builtin_amdgcn_exp2f(acc[s][r] * KEXP);
                    es[s][r] += e; ce += e;
                }
            if (ispos) {
                #pragma unroll
                for (int s = 0; s < 2; s++)
                    #pragma unroll
                    for (int r = 0; r < 4; r++) {
                        int grow = row0 + s * 16 + quad * 4 + r;
                        if (gcol == (grow ^ BATCH)) {
                            float d = acc[s][r];       // raw dot; finalize scales
                            pp[grow] = d;
                            pp[grow ^ BATCH] = d;      // symmetric partner
                        }
                    }
            }
        }
        // column partial sums (transposed contribution), skip on diag blocks
        if (!diagblk) {
            ce += __shfl_xor(ce, 16);
            ce += __shfl_xor(ce, 32);
            if (lane < 16) colbuf[wave][t * CT + l15] = ce;
        }
    };

    // NT=8, unrolled by 2: load next tile into the idle buffer, compute cur.
    #pragma unroll
    for (int t = 0; t < NT; t += 2) {
        const char* g1 = gB + (size_t)(t + 1) * CT * 512;
        #pragma unroll
        for (int ks = 0; ks < 8; ks++)
            bfB[ks] = *(const bfrag8*)(g1 + ks * 64);
        compute_tile(t, bfA);
        if (t + 2 < NT) {
            const char* g2 = gB + (size_t)(t + 2) * CT * 512;
            #pragma unroll
            for (int ks = 0; ks < 8; ks++)
                bfA[ks] = *(const bfrag8*)(g2 + ks * 64);
        }
        compute_tile(t + 1, bfB);
    }

    // row-side: reduce es across the 16 column-lanes, write ep[bj][row]
    #pragma unroll
    for (int s = 0; s < 2; s++)
        #pragma unroll
        for (int r = 0; r < 4; r++) {
            float e = es[s][r];
            #pragma unroll
            for (int m = 1; m < 16; m <<= 1) e += __shfl_xor(e, m);
            if (l15 == 0)
                ep[(size_t)bj * N_ROWS + row0 + s * 16 + quad * 4 + r] = e;
        }

    // col-side: sum the 4 wave partials, write ep[bi][cols of bj]
    __syncthreads();   // the only barrier in the kernel
    if (!diagblk && tid < BR) {
        float v = colbuf[0][tid] + colbuf[1][tid] + colbuf[2][tid] + colbuf[3][tid];
        ep[(size_t)bi * N_ROWS + bj * BR + tid] = v;
    }
}

// ---------------- Kernel C: combine + log + final reduce ---------------
__global__ __launch_bounds__(256) void finalize_kernel(
    const float* __restrict__ ep, const float* __restrict__ pp,
    float* __restrict__ out) {
    int tid = threadIdx.x;
    int i = blockIdx.x * 256 + tid;
    float e = 0.0f;
    #pragma unroll
    for (int s = 0; s < NB; s++) e += ep[(size_t)s * N_ROWS + i];
    float v = __logf(e) - 2.0f * pp[i];
    #pragma unroll
    for (int m = 32; m; m >>= 1) v += __shfl_xor(v, m);
    __shared__ float wsum[4];
    if ((tid & 63) == 0) wsum[tid >> 6] = v;
    __syncthreads();
    if (tid == 0)
        atomicAdd(out, (wsum[0] + wsum[1] + wsum[2] + wsum[3]) * (1.0f / N_ROWS));
}

extern "C" void kernel_launch(void* const* d_in, const int* in_sizes, int n_in,
                              void* d_out, int out_size, void* d_ws, size_t ws_size,
                              hipStream_t stream) {
    const float* zA = (const float*)d_in[0];
    const float* zB = (const float*)d_in[1];
    float* out = (float*)d_out;
    char* ws = (char*)d_ws;
    __hip_bfloat16* zn = (__hip_bfloat16*)ws;                       // 4 MB
    float* ep = (float*)(ws + (size_t)N_ROWS * DIM * 2);            // 64*8192 floats (2 MB)
    float* pp = ep + (size_t)NB * N_ROWS;                           // 8192 floats

    hipMemsetAsync(out, 0, sizeof(float), stream);
    normalize_kernel<<<N_ROWS / 4, 256, 0, stream>>>(zA, zB, zn);
    ntxent_main<<<NBLK, 256, 0, stream>>>(zn, ep, pp);
    finalize_kernel<<<N_ROWS / 256, 256, 0, stream>>>(ep, pp, out);
}

// Round 5
// 151.283 us; speedup vs baseline: 1.1148x; 1.1148x over previous
//
#include <hip/hip_runtime.h>
#include <hip/hip_bf16.h>

#define N_ROWS 8192
#define BATCH 4096
#define DIM 256

#define NB 64           // 128-row blocks along each side
#define BR 128          // rows (and cols) per pair-block side
#define CT 16           // cols per tile
#define NT 8            // tiles per block (BR/CT)
#define NBLK (NB * (NB + 1) / 2)   // 2080 pair blocks
#define KEXP 2.8853900817779268f   // 2*log2(e): exp(2*dot) = exp2(dot*KEXP)

typedef __attribute__((ext_vector_type(8))) short bfrag8;
typedef __attribute__((ext_vector_type(4))) float facc4;

// ---------------- Kernel A: normalize + cast to bf16 -------------------
__global__ __launch_bounds__(256) void normalize_kernel(
    const float* __restrict__ zA, const float* __restrict__ zB,
    __hip_bfloat16* __restrict__ zn) {
    int tid = threadIdx.x;
    int wave = tid >> 6, lane = tid & 63;
    int row = blockIdx.x * 4 + wave;
    const float* src = (row < BATCH) ? (zA + (size_t)row * DIM)
                                     : (zB + (size_t)(row - BATCH) * DIM);
    float4 v = ((const float4*)src)[lane];
    float ss = v.x * v.x + v.y * v.y + v.z * v.z + v.w * v.w;
    #pragma unroll
    for (int m = 32; m; m >>= 1) ss += __shfl_xor(ss, m);
    float inv = 1.0f / fmaxf(sqrtf(ss), 1e-8f);
    union { ushort4 u; __hip_bfloat16 h[4]; } o;
    o.h[0] = __float2bfloat16(v.x * inv);
    o.h[1] = __float2bfloat16(v.y * inv);
    o.h[2] = __float2bfloat16(v.z * inv);
    o.h[3] = __float2bfloat16(v.w * inv);
    ((ushort4*)zn)[(size_t)row * (DIM / 4) + lane] = o.u;
}

// ---------------- Kernel B: symmetric pair-block sim + exp-sum ---------
// Grid: 2080 blocks, one per unordered pair (bi <= bj):
//   row-sums of exp -> ep[rows of bi][slot bj]
//   col-sums of exp -> ep[cols of bj][slot bi]   (bi != bj only)
// ep layout is [row][NB] (transposed vs rounds 2-4) so finalize reads 64
// CONSECUTIVE floats per row -- the old [chunk][row] layout made finalize
// walk 32KB strides (channel aliasing, +16us of "rest" in the totals).
//
// NO LDS staging, NO in-loop barriers (round-4 concept). B fragments load
// straight from L2 into registers, double-buffered. Round 4's failure was
// the (256,3) 170-reg cap: demand ~190 -> bfB spilled (WRITE_SIZE 30 MB).
// (256,2) caps at 256 regs: a[2][8]=64 + bfA/bfB=64 + ~60 misc fits clean.
__global__ __launch_bounds__(256, 2) void ntxent_main(
    const __hip_bfloat16* __restrict__ zn_,
    float* __restrict__ ep, float* __restrict__ pp) {
    const char* zn = (const char*)zn_;
    __shared__ float colbuf[4][BR];
    int tid = threadIdx.x, lane = tid & 63, wave = tid >> 6;
    int quad = lane >> 4, l15 = lane & 15;

    // XCD-aware swizzle (bijective: 2080 % 8 == 0)
    int bid = blockIdx.x;
    int k = (bid & 7) * (NBLK / 8) + (bid >> 3);

    // decode linear pair id -> (bi, bj), bi <= bj
    int bi = (int)(0.5f * (129.0f - sqrtf(16641.0f - 8.0f * (float)k)));
    if (bi < 0) bi = 0;
    if (bi > NB - 1) bi = NB - 1;
    while (bi * (129 - bi) / 2 > k) --bi;
    while ((bi + 1) * (128 - bi) / 2 <= k) ++bi;
    int bj = bi + (k - bi * (129 - bi) / 2);
    bool diagblk = (bi == bj);

    int row0 = bi * BR + wave * 32;   // this wave's 32 rows

    // B column base for this lane: col = bj*BR + t*CT + l15, bytes quad*16+ks*64
    const char* gB = zn + (size_t)(bj * BR + l15) * 512 + quad * 16;

    bfrag8 bfA[8], bfB[8];
    #pragma unroll
    for (int ks = 0; ks < 8; ks++)              // prefetch tile 0
        bfA[ks] = *(const bfrag8*)(gB + ks * 64);

    // A fragments: 2 tiles of 16 rows, full K=256 (overlaps tile-0 loads)
    bfrag8 a[2][8];
    #pragma unroll
    for (int s = 0; s < 2; s++) {
        const char* ap = zn + (size_t)(row0 + s * 16 + l15) * 512 + quad * 16;
        #pragma unroll
        for (int ks = 0; ks < 8; ks++)
            a[s][ks] = *(const bfrag8*)(ap + ks * 64);
    }

    float es[2][4];
    #pragma unroll
    for (int s = 0; s < 2; s++)
        #pragma unroll
        for (int r = 0; r < 4; r++) es[s][r] = 0.f;

    auto compute_tile = [&](int t, bfrag8 (&bf)[8]) {
        facc4 acc[2];
        acc[0] = (facc4){0.f, 0.f, 0.f, 0.f};
        acc[1] = (facc4){0.f, 0.f, 0.f, 0.f};
        #pragma unroll
        for (int ks = 0; ks < 8; ks++) {
            acc[0] = __builtin_amdgcn_mfma_f32_16x16x32_bf16(a[0][ks], bf[ks], acc[0], 0, 0, 0);
            acc[1] = __builtin_amdgcn_mfma_f32_16x16x32_bf16(a[1][ks], bf[ks], acc[1], 0, 0, 0);
        }
        int ctile = bj * BR + t * CT;
        int gcol = ctile + l15;
        float ce = 0.0f;
        bool isdiag = (ctile >> 5) == (row0 >> 5);             // only in diag blocks
        bool ispos  = (ctile >> 5) == ((row0 ^ BATCH) >> 5);   // only in (bi, bi+32)

        if (isdiag) {
            #pragma unroll
            for (int s = 0; s < 2; s++)
                #pragma unroll
                for (int r = 0; r < 4; r++) {
                    int grow = row0 + s * 16 + quad * 4 + r;
                    float e = __builtin_amdgcn_exp2f(acc[s][r] * KEXP);
                    if (gcol == grow) e = 0.0f;   // mask true diagonal
                    es[s][r] += e; ce += e;
                }
        } else {
            #pragma unroll
            for (int s = 0; s < 2; s++)
                #pragma unroll
                for (int r = 0; r < 4; r++) {
                    float e = __builtin_amdgcn_exp2f(acc[s][r] * KEXP);
                    es[s][r] += e; ce += e;
                }
            if (ispos) {
                #pragma unroll
                for (int s = 0; s < 2; s++)
                    #pragma unroll
                    for (int r = 0; r < 4; r++) {
                        int grow = row0 + s * 16 + quad * 4 + r;
                        if (gcol == (grow ^ BATCH)) {
                            float d = acc[s][r];       // raw dot; finalize scales
                            pp[grow] = d;
                            pp[grow ^ BATCH] = d;      // symmetric partner
                        }
                    }
            }
        }
        // column partial sums (transposed contribution), skip on diag blocks
        if (!diagblk) {
            ce += __shfl_xor(ce, 16);
            ce += __shfl_xor(ce, 32);
            if (lane < 16) colbuf[wave][t * CT + l15] = ce;
        }
    };

    // NT=8, unrolled by 2: load next tile into the idle buffer, compute cur.
    #pragma unroll
    for (int t = 0; t < NT; t += 2) {
        const char* g1 = gB + (size_t)(t + 1) * CT * 512;
        #pragma unroll
        for (int ks = 0; ks < 8; ks++)
            bfB[ks] = *(const bfrag8*)(g1 + ks * 64);
        compute_tile(t, bfA);
        if (t + 2 < NT) {
            const char* g2 = gB + (size_t)(t + 2) * CT * 512;
            #pragma unroll
            for (int ks = 0; ks < 8; ks++)
                bfA[ks] = *(const bfrag8*)(g2 + ks * 64);
        }
        compute_tile(t + 1, bfB);
    }

    // row-side: reduce es across the 16 column-lanes, write ep[row][bj]
    #pragma unroll
    for (int s = 0; s < 2; s++)
        #pragma unroll
        for (int r = 0; r < 4; r++) {
            float e = es[s][r];
            #pragma unroll
            for (int m = 1; m < 16; m <<= 1) e += __shfl_xor(e, m);
            if (l15 == 0)
                ep[(size_t)(row0 + s * 16 + quad * 4 + r) * NB + bj] = e;
        }

    // col-side: sum the 4 wave partials, write ep[cols of bj][bi]
    __syncthreads();   // the only barrier in the kernel
    if (!diagblk && tid < BR) {
        float v = colbuf[0][tid] + colbuf[1][tid] + colbuf[2][tid] + colbuf[3][tid];
        ep[(size_t)(bj * BR + tid) * NB + bi] = v;
    }
}

// ---------------- Kernel C: combine + log + final reduce ---------------
__global__ __launch_bounds__(256) void finalize_kernel(
    const float* __restrict__ ep, const float* __restrict__ pp,
    float* __restrict__ out) {
    int tid = threadIdx.x;
    int i = blockIdx.x * 256 + tid;
    // ep[i][0..63]: 64 consecutive floats -> 16 x float4 (was 64 x 32KB-stride)
    const float4* epr = (const float4*)(ep + (size_t)i * NB);
    float e = 0.0f;
    #pragma unroll
    for (int s = 0; s < NB / 4; s++) {
        float4 v = epr[s];
        e += (v.x + v.y) + (v.z + v.w);
    }
    float v = __logf(e) - 2.0f * pp[i];
    #pragma unroll
    for (int m = 32; m; m >>= 1) v += __shfl_xor(v, m);
    __shared__ float wsum[4];
    if ((tid & 63) == 0) wsum[tid >> 6] = v;
    __syncthreads();
    if (tid == 0)
        atomicAdd(out, (wsum[0] + wsum[1] + wsum[2] + wsum[3]) * (1.0f / N_ROWS));
}

extern "C" void kernel_launch(void* const* d_in, const int* in_sizes, int n_in,
                              void* d_out, int out_size, void* d_ws, size_t ws_size,
                              hipStream_t stream) {
    const float* zA = (const float*)d_in[0];
    const float* zB = (const float*)d_in[1];
    float* out = (float*)d_out;
    char* ws = (char*)d_ws;
    __hip_bfloat16* zn = (__hip_bfloat16*)ws;                       // 4 MB
    float* ep = (float*)(ws + (size_t)N_ROWS * DIM * 2);            // 8192*64 floats (2 MB)
    float* pp = ep + (size_t)N_ROWS * NB;                           // 8192 floats

    hipMemsetAsync(out, 0, sizeof(float), stream);
    normalize_kernel<<<N_ROWS / 4, 256, 0, stream>>>(zA, zB, zn);
    ntxent_main<<<NBLK, 256, 0, stream>>>(zn, ep, pp);
    finalize_kernel<<<N_ROWS / 256, 256, 0, stream>>>(ep, pp, out);
}

// Round 6
// 105.250 us; speedup vs baseline: 1.6024x; 1.4374x over previous
//
#include <hip/hip_runtime.h>
#include <hip/hip_bf16.h>

#define N_ROWS 8192
#define BATCH 4096
#define DIM 256

#define NB 64           // 128-row blocks along each side
#define BR 128          // rows (and cols) per pair-block side
#define CT 32           // cols per LDS tile (was 16: halves step count)
#define NT 4            // tiles per block (BR/CT)
#define NBLK (NB * (NB + 1) / 2)   // 2080 pair blocks
#define TILEB (CT * 512)           // 16 KB per tile, LINEAR (no pad; XOR swizzle)
#define KEXP 2.8853900817779268f   // 2*log2(e): exp(2*dot) = exp2(dot*KEXP)

typedef __attribute__((ext_vector_type(8))) short bfrag8;
typedef __attribute__((ext_vector_type(4))) float facc4;

// async global->LDS, 16B per lane; LDS dest = wave-uniform base + lane*16
#define GLOAD_LDS16(g, l) __builtin_amdgcn_global_load_lds( \
    (const __attribute__((address_space(1))) unsigned int*)(g), \
    (__attribute__((address_space(3))) unsigned int*)(l), 16, 0, 0)

// ---------------- Kernel A: normalize + cast to bf16 -------------------
__global__ __launch_bounds__(256) void normalize_kernel(
    const float* __restrict__ zA, const float* __restrict__ zB,
    __hip_bfloat16* __restrict__ zn) {
    int tid = threadIdx.x;
    int wave = tid >> 6, lane = tid & 63;
    int row = blockIdx.x * 4 + wave;
    const float* src = (row < BATCH) ? (zA + (size_t)row * DIM)
                                     : (zB + (size_t)(row - BATCH) * DIM);
    float4 v = ((const float4*)src)[lane];
    float ss = v.x * v.x + v.y * v.y + v.z * v.z + v.w * v.w;
    #pragma unroll
    for (int m = 32; m; m >>= 1) ss += __shfl_xor(ss, m);
    float inv = 1.0f / fmaxf(sqrtf(ss), 1e-8f);
    union { ushort4 u; __hip_bfloat16 h[4]; } o;
    o.h[0] = __float2bfloat16(v.x * inv);
    o.h[1] = __float2bfloat16(v.y * inv);
    o.h[2] = __float2bfloat16(v.z * inv);
    o.h[3] = __float2bfloat16(v.w * inv);
    ((ushort4*)zn)[(size_t)row * (DIM / 4) + lane] = o.u;
}

// ---------------- Kernel B: symmetric pair-block sim + exp-sum ---------
// Grid: 2080 blocks, one per unordered pair (bi <= bj):
//   row-sums of exp -> ep[rows of bi][slot bj]
//   col-sums of exp -> ep[cols of bj][slot bi]   (bi != bj only)
// One write per ep cell, no atomics, no memset. ep layout [row][NB] so
// finalize reads 64 consecutive floats (round-5 fix, verified: rest 31->19us).
//
// Step-overhead attack (rounds 0-5 evidence: time invariant to FLOPs and
// staging bytes, ~3.4k cy/step wall vs ~400 cy content): CT 16->32 halves
// step & barrier count; staging via global_load_lds (async DMA, no VGPR
// roundtrip). Linear LDS dest forces T2 XOR-swizzle: LDS[col*512 + o]
// holds global[col*512 + (o ^ ((col&7)<<4))]; ds_read applies the same
// involution -> 2-way banks (free), same as the old +16 pad.
__global__ __launch_bounds__(256, 3) void ntxent_main(
    const __hip_bfloat16* __restrict__ zn_,
    float* __restrict__ ep, float* __restrict__ pp) {
    const char* zn = (const char*)zn_;
    __shared__ char lds[2 * TILEB] __attribute__((aligned(1024)));
    __shared__ float colbuf[4][BR];
    int tid = threadIdx.x, lane = tid & 63, wave = tid >> 6;
    int quad = lane >> 4, l15 = lane & 15;

    // XCD-aware swizzle (bijective: 2080 % 8 == 0)
    int bid = blockIdx.x;
    int k = (bid & 7) * (NBLK / 8) + (bid >> 3);

    // decode linear pair id -> (bi, bj), bi <= bj
    int bi = (int)(0.5f * (129.0f - sqrtf(16641.0f - 8.0f * (float)k)));
    if (bi < 0) bi = 0;
    if (bi > NB - 1) bi = NB - 1;
    while (bi * (129 - bi) / 2 > k) --bi;
    while ((bi + 1) * (128 - bi) / 2 <= k) ++bi;
    int bj = bi + (k - bi * (129 - bi) / 2);
    bool diagblk = (bi == bj);

    int row0 = bi * BR + wave * 32;   // this wave's 32 rows
    const char* gBt = zn + (size_t)bj * BR * 512;   // + t*TILEB per tile

    // Staging source offsets (per lane, per call c=0..3):
    //   col = wave*8 + 2c + h (h = lane>>5), dest ofs = (lane&31)*16,
    //   src = col*512 + (destofs ^ ((col&7)<<4))   [inverse swizzle]
    int h = lane >> 5;
    int olane = (lane & 31) * 16;
    unsigned sofs[4];
    #pragma unroll
    for (int c = 0; c < 4; c++) {
        int col = wave * 8 + 2 * c + h;
        sofs[c] = (unsigned)(col * 512 + (olane ^ ((col & 7) << 4)));
    }

    // stage tile 0 (async; drained by the first __syncthreads)
    #pragma unroll
    for (int c = 0; c < 4; c++)
        GLOAD_LDS16(gBt + sofs[c], lds + wave * 4096 + c * 1024);

    // A fragments: 2 tiles of 16 rows, full K=256 (overlaps tile-0 DMA)
    bfrag8 a[2][8];
    #pragma unroll
    for (int s = 0; s < 2; s++) {
        const char* ap = zn + (size_t)(row0 + s * 16 + l15) * 512 + quad * 16;
        #pragma unroll
        for (int ks = 0; ks < 8; ks++)
            a[s][ks] = *(const bfrag8*)(ap + ks * 64);
    }

    float es[2][4];
    #pragma unroll
    for (int s = 0; s < 2; s++)
        #pragma unroll
        for (int r = 0; r < 4; r++) es[s][r] = 0.f;

    __syncthreads();

    for (int t = 0; t < NT; t++) {
        char* cur = lds + (t & 1) * TILEB;
        char* nxt = lds + ((t + 1) & 1) * TILEB;
        if (t + 1 < NT) {
            const char* g = gBt + (size_t)(t + 1) * TILEB;
            #pragma unroll
            for (int c = 0; c < 4; c++)
                GLOAD_LDS16(g + sofs[c], nxt + wave * 4096 + c * 1024);
        }

        // two 16-col subtiles per step
        #pragma unroll
        for (int sub = 0; sub < 2; sub++) {
            int c2 = sub * 16 + l15;
            const char* bp = cur + c2 * 512;
            unsigned sw = (unsigned)((c2 & 7) << 4);
            bfrag8 bf[8];
            #pragma unroll
            for (int ks = 0; ks < 8; ks++) {
                unsigned o = (unsigned)(quad * 16 + ks * 64);
                bf[ks] = *(const bfrag8*)(bp + (o ^ sw));
            }

            facc4 acc[2];
            acc[0] = (facc4){0.f, 0.f, 0.f, 0.f};
            acc[1] = (facc4){0.f, 0.f, 0.f, 0.f};
            #pragma unroll
            for (int ks = 0; ks < 8; ks++) {
                acc[0] = __builtin_amdgcn_mfma_f32_16x16x32_bf16(a[0][ks], bf[ks], acc[0], 0, 0, 0);
                acc[1] = __builtin_amdgcn_mfma_f32_16x16x32_bf16(a[1][ks], bf[ks], acc[1], 0, 0, 0);
            }

            int ctile = bj * BR + t * CT + sub * 16;
            int gcol = ctile + l15;
            float ce = 0.0f;
            bool isdiag = (ctile >> 5) == (row0 >> 5);             // diag blocks only
            bool ispos  = (ctile >> 5) == ((row0 ^ BATCH) >> 5);   // (bi, bi+32) only

            if (isdiag) {
                #pragma unroll
                for (int s = 0; s < 2; s++)
                    #pragma unroll
                    for (int r = 0; r < 4; r++) {
                        int grow = row0 + s * 16 + quad * 4 + r;
                        float e = __builtin_amdgcn_exp2f(acc[s][r] * KEXP);
                        if (gcol == grow) e = 0.0f;   // mask true diagonal
                        es[s][r] += e; ce += e;
                    }
            } else {
                #pragma unroll
                for (int s = 0; s < 2; s++)
                    #pragma unroll
                    for (int r = 0; r < 4; r++) {
                        float e = __builtin_amdgcn_exp2f(acc[s][r] * KEXP);
                        es[s][r] += e; ce += e;
                    }
                if (ispos) {
                    #pragma unroll
                    for (int s = 0; s < 2; s++)
                        #pragma unroll
                        for (int r = 0; r < 4; r++) {
                            int grow = row0 + s * 16 + quad * 4 + r;
                            if (gcol == (grow ^ BATCH)) {
                                float d = acc[s][r];       // raw dot; finalize scales
                                pp[grow] = d;
                                pp[grow ^ BATCH] = d;      // symmetric partner
                            }
                        }
                }
            }
            // column partial sums (transposed contribution), skip on diag blocks
            if (!diagblk) {
                ce += __shfl_xor(ce, 16);
                ce += __shfl_xor(ce, 32);
                if (lane < 16) colbuf[wave][t * CT + sub * 16 + l15] = ce;
            }
        }

        __syncthreads();   // one barrier per 32-col step (was per 16-col)
    }

    // row-side: reduce es across the 16 column-lanes, write ep[row][bj]
    #pragma unroll
    for (int s = 0; s < 2; s++)
        #pragma unroll
        for (int r = 0; r < 4; r++) {
            float e = es[s][r];
            #pragma unroll
            for (int m = 1; m < 16; m <<= 1) e += __shfl_xor(e, m);
            if (l15 == 0)
                ep[(size_t)(row0 + s * 16 + quad * 4 + r) * NB + bj] = e;
        }

    // col-side: sum the 4 wave partials, write ep[cols of bj][bi]
    if (!diagblk && tid < BR) {
        float v = colbuf[0][tid] + colbuf[1][tid] + colbuf[2][tid] + colbuf[3][tid];
        ep[(size_t)(bj * BR + tid) * NB + bi] = v;
    }
}

// ---------------- Kernel C: combine + log + final reduce ---------------
__global__ __launch_bounds__(256) void finalize_kernel(
    const float* __restrict__ ep, const float* __restrict__ pp,
    float* __restrict__ out) {
    int tid = threadIdx.x;
    int i = blockIdx.x * 256 + tid;
    // ep[i][0..63]: 64 consecutive floats -> 16 x float4
    const float4* epr = (const float4*)(ep + (size_t)i * NB);
    float e = 0.0f;
    #pragma unroll
    for (int s = 0; s < NB / 4; s++) {
        float4 v = epr[s];
        e += (v.x + v.y) + (v.z + v.w);
    }
    float v = __logf(e) - 2.0f * pp[i];
    #pragma unroll
    for (int m = 32; m; m >>= 1) v += __shfl_xor(v, m);
    __shared__ float wsum[4];
    if ((tid & 63) == 0) wsum[tid >> 6] = v;
    __syncthreads();
    if (tid == 0)
        atomicAdd(out, (wsum[0] + wsum[1] + wsum[2] + wsum[3]) * (1.0f / N_ROWS));
}

extern "C" void kernel_launch(void* const* d_in, const int* in_sizes, int n_in,
                              void* d_out, int out_size, void* d_ws, size_t ws_size,
                              hipStream_t stream) {
    const float* zA = (const float*)d_in[0];
    const float* zB = (const float*)d_in[1];
    float* out = (float*)d_out;
    char* ws = (char*)d_ws;
    __hip_bfloat16* zn = (__hip_bfloat16*)ws;                       // 4 MB
    float* ep = (float*)(ws + (size_t)N_ROWS * DIM * 2);            // 8192*64 floats (2 MB)
    float* pp = ep + (size_t)N_ROWS * NB;                           // 8192 floats

    hipMemsetAsync(out, 0, sizeof(float), stream);
    normalize_kernel<<<N_ROWS / 4, 256, 0, stream>>>(zA, zB, zn);
    ntxent_main<<<NBLK, 256, 0, stream>>>(zn, ep, pp);
    finalize_kernel<<<N_ROWS / 256, 256, 0, stream>>>(ep, pp, out);
}